// Round 10
// baseline (3023.969 us; speedup 1.0000x reference)
//
#include <hip/hip_runtime.h>

// GCN on MI355X. R10:
//  - CSR scatter-fill replaced by counting sort into 64-node buckets:
//    bucket_hist (LDS hist) -> single-block scan -> bucket_place (LDS cursors
//    => sequential positions per bucket => L2 write-merging). Record = 4B
//    {dlocal:6b, src:16b}.
//  - aggregation/prop6 = per-bucket LDS accumulation (ds_add_f32), dinv[s]
//    pre-folded into mgemm<0> epilogue: t' = dinv*(h@W);
//    out[d] = relu(dinv[d]*(sum t'[src] + t'[d]) + b).
// Pipeline: deg/hist/dinv | bhist->scan->bplace | xp -> prop6b -> gemm0
//   -> wprep -> [mgemm<0,dinv> -> aggregateb]x2 -> mgemm<2> -> mgemm<3>(+dot)

#define HDIM 128
#define NB1 64  // sort blocks

typedef __attribute__((ext_vector_type(8))) short bf16x8;
typedef __attribute__((ext_vector_type(4))) float f32x4;

__device__ inline unsigned short bf16rn(float f) {
  unsigned u = __float_as_uint(f);
  unsigned r = (u + 0x7FFFu + ((u >> 16) & 1u)) >> 16;
  return (unsigned short)r;
}
__device__ inline float bf16tof(unsigned short h) {
  return __uint_as_float(((unsigned)h) << 16);
}

// ---------------- degree / dinv ----------------

__global__ void init_deg(int* deg, int n) {
  int i = blockIdx.x * blockDim.x + threadIdx.x;
  if (i < n) deg[i] = 1;  // self loop
}

__global__ void hist_kernel(const int* __restrict__ ei, int E, int* __restrict__ deg) {
  int e = blockIdx.x * blockDim.x + threadIdx.x;
  if (e < E) atomicAdd(&deg[ei[E + e]], 1);  // dst = ei[1][e]
}

__global__ void dinv_kernel(const int* __restrict__ deg, float* __restrict__ dinv, int n) {
  int i = blockIdx.x * blockDim.x + threadIdx.x;
  if (i < n) dinv[i] = rsqrtf((float)deg[i]);
}

// ---------------- bucket counting sort ----------------

// per-(bucket,block) histogram: gh[k*NB1 + b]
__global__ __launch_bounds__(1024) void bucket_hist(const int* __restrict__ ei, int E,
                                                    int chunk, int* __restrict__ gh, int nbk) {
  __shared__ int h[1024];
  int tid = threadIdx.x, b = blockIdx.x;
  for (int i = tid; i < nbk; i += 1024) h[i] = 0;
  __syncthreads();
  int s = b * chunk, e = min(E, s + chunk);
  for (int i = s + tid; i < e; i += 1024) atomicAdd(&h[ei[E + i] >> 6], 1);
  __syncthreads();
  for (int k = tid; k < nbk; k += 1024) gh[k * NB1 + b] = h[k];
}

// single-block exclusive scan over M ints (chunked, serial carry)
__global__ __launch_bounds__(256) void scan_kernel(const int* __restrict__ in,
                                                   int* __restrict__ outv, int M) {
  __shared__ int wsum[4];
  __shared__ int carry_s;
  int tid = threadIdx.x, lane = tid & 63, wid = tid >> 6;
  if (tid == 0) carry_s = 0;
  __syncthreads();
  int nchunks = (M + 4095) / 4096;
  for (int c = 0; c < nchunks; ++c) {
    int base = c * 4096 + tid * 16;
    int v[16];
#pragma unroll
    for (int j = 0; j < 16; ++j) {
      int i = base + j;
      v[j] = (i < M) ? in[i] : 0;
    }
    int s = 0;
#pragma unroll
    for (int j = 0; j < 16; ++j) { int t = v[j]; v[j] = s; s += t; }
    int tot = s;
    int inc = tot;
#pragma unroll
    for (int d = 1; d < 64; d <<= 1) {
      int t = __shfl_up(inc, (unsigned)d, 64);
      if (lane >= d) inc += t;
    }
    if (lane == 63) wsum[wid] = inc;
    int texcl = inc - tot;
    __syncthreads();
    int wexcl = 0, ctot = 0;
#pragma unroll
    for (int w = 0; w < 4; ++w) {
      int ws = wsum[w];
      if (w < wid) wexcl += ws;
      ctot += ws;
    }
    int cbase = carry_s + wexcl + texcl;
#pragma unroll
    for (int j = 0; j < 16; ++j) {
      int i = base + j;
      if (i < M) outv[i] = cbase + v[j];
    }
    __syncthreads();
    if (tid == 0) carry_s += ctot;
    __syncthreads();
  }
}

// place records: LDS cursors -> sequential positions per (bucket,block)
__global__ __launch_bounds__(1024) void bucket_place(const int* __restrict__ ei, int E,
                                                     int chunk, const int* __restrict__ ghs,
                                                     unsigned* __restrict__ recs, int nbk) {
  __shared__ int cur[1024];
  int tid = threadIdx.x, b = blockIdx.x;
  for (int k = tid; k < nbk; k += 1024) cur[k] = ghs[k * NB1 + b];
  __syncthreads();
  int s = b * chunk, e = min(E, s + chunk);
  for (int i = s + tid; i < e; i += 1024) {
    int src = ei[i], dst = ei[E + i];
    int k = dst >> 6;
    int pos = atomicAdd(&cur[k], 1);
    recs[pos] = (unsigned)src | ((unsigned)(dst & 63) << 16);
  }
}

// ---------------- layer 0 ----------------

// xp = dinv[node] * x (prescale)
__global__ void xprescale_kernel(const float* __restrict__ x, const float* __restrict__ dinv,
                                 float* __restrict__ xp, int tot) {
  int i = blockIdx.x * blockDim.x + threadIdx.x;
  if (i < tot) xp[i] = x[i] * dinv[i / 6];
}

// bucket-LDS aggregation of 6-dim xp
__global__ __launch_bounds__(256) void prop6b_kernel(const float* __restrict__ xp,
                                                     const float* __restrict__ dinv,
                                                     const int* __restrict__ ghs,
                                                     const unsigned* __restrict__ recs,
                                                     float* __restrict__ aggx,
                                                     int n, int E, int nbk) {
  __shared__ float acc[64][8];
  int tid = threadIdx.x, k = blockIdx.x;
  for (int i = tid; i < 512; i += 256) ((float*)acc)[i] = 0.f;
  int e0 = ghs[k * NB1];
  int e1 = (k + 1 < nbk) ? ghs[(k + 1) * NB1] : E;
  __syncthreads();
  for (int i = e0 + tid; i < e1; i += 256) {
    unsigned r = recs[i];
    int src = r & 0xFFFF, dl = r >> 16;
    const float* xs = &xp[src * 6];
#pragma unroll
    for (int j = 0; j < 6; ++j) atomicAdd(&acc[dl][j], xs[j]);
  }
  __syncthreads();
  for (int flat = tid; flat < 384; flat += 256) {
    int dl = flat / 6, j = flat - dl * 6;
    int d = k * 64 + dl;
    if (d < n) aggx[d * 6 + j] = dinv[d] * (acc[dl][j] + xp[d * 6 + j]);
  }
}

// h0 = relu(aggx @ W0 + b0) -> bf16. 16 nodes per 256-block.
__global__ __launch_bounds__(256) void gemm0_kernel(const float* __restrict__ aggx,
                                                    const float* __restrict__ W0,
                                                    const float* __restrict__ b0,
                                                    unsigned short* __restrict__ out, int n) {
  __shared__ float Ws[6 * 128];
  __shared__ float bs[128];
  for (int i = threadIdx.x; i < 6 * 128; i += 256) Ws[i] = W0[i];
  if (threadIdx.x < 128) bs[threadIdx.x] = b0[threadIdx.x];
  __syncthreads();
  int f = threadIdx.x & 127;
  int h = threadIdx.x >> 7;
  int base = blockIdx.x * 16;
#pragma unroll
  for (int j = 0; j < 8; ++j) {
    int nd = base + h * 8 + j;
    if (nd < n) {
      float acc = bs[f];
#pragma unroll
      for (int kk = 0; kk < 6; ++kk) acc += aggx[nd * 6 + kk] * Ws[kk * 128 + f];
      out[(size_t)nd * HDIM + f] = bf16rn(fmaxf(acc, 0.f));
    }
  }
}

// ---------------- weight prep (fp32 -> bf16 MFMA B-fragment order) --------
__global__ __launch_bounds__(256) void wprep_kernel(const float* __restrict__ w1,
                                                    const float* __restrict__ w2,
                                                    const float* __restrict__ rw0,
                                                    const float* __restrict__ rw1,
                                                    unsigned short* __restrict__ wtf) {
  int widx = blockIdx.y;
  const float* W = (widx == 0) ? w1 : (widx == 1) ? w2 : (widx == 2) ? rw0 : rw1;
  int c = blockIdx.x * 256 + threadIdx.x;  // 0..2047
  int l = c & 63, kk = (c >> 6) & 3, ft = c >> 8;
  int f = ft * 16 + (l & 15);
  int k0 = kk * 32 + ((l >> 4) << 3);
  unsigned short v[8];
#pragma unroll
  for (int j = 0; j < 8; ++j) v[j] = bf16rn(W[(size_t)(k0 + j) * 128 + f]);
  uint4 pk;
  pk.x = (unsigned)v[0] | ((unsigned)v[1] << 16);
  pk.y = (unsigned)v[2] | ((unsigned)v[3] << 16);
  pk.z = (unsigned)v[4] | ((unsigned)v[5] << 16);
  pk.w = (unsigned)v[6] | ((unsigned)v[7] << 16);
  *(uint4*)&wtf[((size_t)widx * 16384) + (size_t)c * 8] = pk;
}

// ---------------- MFMA GEMM [n,128](bf16) @ W[128,128] ----------------
// ACT: 0 = raw * dinv[row] -> bf16 (prescaled message table)
//      2 = bias + leaky -> bf16 ; 3 = bias + leaky + dot rw2 + rb2 -> fp32
template <int ACT>
__global__ __launch_bounds__(256) void mgemm_kernel(const unsigned short* __restrict__ in,
                                                    const unsigned short* __restrict__ wtf,
                                                    const float* __restrict__ bias,
                                                    unsigned short* __restrict__ out, int n,
                                                    const float* __restrict__ dinv,
                                                    const float* __restrict__ rw2,
                                                    const float* __restrict__ rb2,
                                                    float* __restrict__ out1) {
  __shared__ unsigned short Alds[8192];   // 16KB swizzled A tile
  __shared__ unsigned short Wlds[16384];  // 32KB fragment-ordered W
  int tid = threadIdx.x;
  int rowBase = blockIdx.x * 64;
  {
    const uint4* src = (const uint4*)wtf;
    uint4* dst = (uint4*)Wlds;
#pragma unroll
    for (int c = 0; c < 8; ++c) dst[c * 256 + tid] = src[c * 256 + tid];
  }
  {
    int k8 = tid & 15, tr = tid >> 4;
#pragma unroll
    for (int c = 0; c < 4; ++c) {
      int row = tr + c * 16;
      int gr = rowBase + row;
      uint4 v = make_uint4(0u, 0u, 0u, 0u);
      if (gr < n) v = *(const uint4*)&in[(size_t)gr * HDIM + k8 * 8];
      int srow = row ^ (k8 & 7);
      *(uint4*)&Alds[k8 * 512 + srow * 8] = v;
    }
  }
  __syncthreads();
  int wv = tid >> 6, lane = tid & 63;
  int l16 = lane >> 4, fcol = lane & 15;
  int lrow = wv * 16 + fcol;
  bf16x8 af[4];
#pragma unroll
  for (int kk = 0; kk < 4; ++kk) {
    int k8 = kk * 4 + l16;
    int srow = lrow ^ (k8 & 7);
    af[kk] = *(const bf16x8*)&Alds[k8 * 512 + srow * 8];
  }
  f32x4 acc[8];
#pragma unroll
  for (int ft = 0; ft < 8; ++ft) acc[ft] = (f32x4)(0.f);
#pragma unroll
  for (int ft = 0; ft < 8; ++ft) {
#pragma unroll
    for (int kk = 0; kk < 4; ++kk) {
      bf16x8 bfr = *(const bf16x8*)&Wlds[(((ft * 4 + kk) * 64) + lane) * 8];
      acc[ft] = __builtin_amdgcn_mfma_f32_16x16x32_bf16(af[kk], bfr, acc[ft], 0, 0, 0);
    }
  }
  int orow0 = rowBase + wv * 16 + l16 * 4;  // D: col=lane&15, row=(lane>>4)*4+reg

  if (ACT == 3) {
    float p[4] = {0.f, 0.f, 0.f, 0.f};
#pragma unroll
    for (int ft = 0; ft < 8; ++ft) {
      int f = ft * 16 + fcol;
      float bb = bias[f], ww = rw2[f];
#pragma unroll
      for (int r = 0; r < 4; ++r) {
        float v = acc[ft][r] + bb;
        v = v > 0.f ? v : 0.01f * v;
        p[r] += v * ww;
      }
    }
#pragma unroll
    for (int d = 1; d < 16; d <<= 1) {
#pragma unroll
      for (int r = 0; r < 4; ++r) p[r] += __shfl_xor(p[r], d, 64);
    }
    if (fcol == 0) {
      float rb = rb2[0];
#pragma unroll
      for (int r = 0; r < 4; ++r) {
        int row = orow0 + r;
        if (row < n) out1[row] = p[r] + rb;
      }
    }
    return;
  }

  float dv[4];
  if (ACT == 0) {
#pragma unroll
    for (int r = 0; r < 4; ++r) {
      int row = orow0 + r;
      dv[r] = (row < n) ? dinv[row] : 0.f;
    }
  }
#pragma unroll
  for (int ft = 0; ft < 8; ++ft) {
    int f = ft * 16 + fcol;
    float bb = (ACT == 2) ? bias[f] : 0.f;
#pragma unroll
    for (int r = 0; r < 4; ++r) {
      int row = orow0 + r;
      if (row < n) {
        float v = acc[ft][r];
        if (ACT == 0) v *= dv[r];
        if (ACT == 2) {
          v += bb;
          v = v > 0.f ? v : 0.01f * v;
        }
        out[(size_t)row * HDIM + f] = bf16rn(v);
      }
    }
  }
}

// ---------------- aggregation: per-bucket LDS accumulation ----------------
// t is prescaled (t' = dinv*(h@W)). out[d] = relu(dinv[d]*(sum+t'[d]) + b)
__global__ __launch_bounds__(256) void aggregateb_kernel(const unsigned short* __restrict__ t,
                                                         const float* __restrict__ dinv,
                                                         const int* __restrict__ ghs,
                                                         const unsigned* __restrict__ recs,
                                                         const float* __restrict__ bias,
                                                         unsigned short* __restrict__ out,
                                                         int n, int E, int nbk) {
  __shared__ float acc[64][128];  // 32KB
  int tid = threadIdx.x, k = blockIdx.x;
  {
    float4* az = (float4*)acc;
    for (int i = tid; i < 2048; i += 256) az[i] = make_float4(0.f, 0.f, 0.f, 0.f);
  }
  int e0 = ghs[k * NB1];
  int e1 = (k + 1 < nbk) ? ghs[(k + 1) * NB1] : E;
  __syncthreads();
  int wv = tid >> 6, lane = tid & 63;
  const ushort2* tf = (const ushort2*)t + lane;  // row r at tf[r*64]
  int i = e0 + wv;
  for (; i + 12 < e1; i += 16) {  // 4 gathers in flight per wave
    unsigned r0 = recs[i], r1 = recs[i + 4], r2 = recs[i + 8], r3 = recs[i + 12];
    ushort2 u0 = tf[(size_t)(r0 & 0xFFFF) * 64];
    ushort2 u1 = tf[(size_t)(r1 & 0xFFFF) * 64];
    ushort2 u2 = tf[(size_t)(r2 & 0xFFFF) * 64];
    ushort2 u3 = tf[(size_t)(r3 & 0xFFFF) * 64];
    int f = lane * 2;
    atomicAdd(&acc[r0 >> 16][f], bf16tof(u0.x));
    atomicAdd(&acc[r0 >> 16][f + 1], bf16tof(u0.y));
    atomicAdd(&acc[r1 >> 16][f], bf16tof(u1.x));
    atomicAdd(&acc[r1 >> 16][f + 1], bf16tof(u1.y));
    atomicAdd(&acc[r2 >> 16][f], bf16tof(u2.x));
    atomicAdd(&acc[r2 >> 16][f + 1], bf16tof(u2.y));
    atomicAdd(&acc[r3 >> 16][f], bf16tof(u3.x));
    atomicAdd(&acc[r3 >> 16][f + 1], bf16tof(u3.y));
  }
  for (; i < e1; i += 4) {
    unsigned r = recs[i];
    ushort2 u = tf[(size_t)(r & 0xFFFF) * 64];
    int f = lane * 2;
    atomicAdd(&acc[r >> 16][f], bf16tof(u.x));
    atomicAdd(&acc[r >> 16][f + 1], bf16tof(u.y));
  }
  __syncthreads();
  for (int flat = tid; flat < 8192; flat += 256) {
    int dl = flat >> 7, f = flat & 127;
    int d = k * 64 + dl;
    if (d < n) {
      float self = bf16tof(t[(size_t)d * HDIM + f]);
      float v = dinv[d] * (acc[dl][f] + self) + bias[f];
      out[(size_t)d * HDIM + f] = bf16rn(fmaxf(v, 0.f));
    }
  }
}

// ---------------- host ----------------

static inline size_t align256(size_t x) { return (x + 255) & ~(size_t)255; }

extern "C" void kernel_launch(void* const* d_in, const int* in_sizes, int n_in,
                              void* d_out, int out_size, void* d_ws, size_t ws_size,
                              hipStream_t stream) {
  const float* x   = (const float*)d_in[0];
  const int*   ei  = (const int*)d_in[1];
  const float* W0  = (const float*)d_in[2];
  const float* b0  = (const float*)d_in[3];
  const float* W1  = (const float*)d_in[4];
  const float* b1  = (const float*)d_in[5];
  const float* W2  = (const float*)d_in[6];
  const float* b2  = (const float*)d_in[7];
  const float* Rw0 = (const float*)d_in[8];
  const float* Rb0 = (const float*)d_in[9];
  const float* Rw1 = (const float*)d_in[10];
  const float* Rb1 = (const float*)d_in[11];
  const float* Rw2 = (const float*)d_in[12];
  const float* Rb2 = (const float*)d_in[13];
  float* out = (float*)d_out;

  int N = in_sizes[0] / 6;
  int E = in_sizes[1] / 2;
  int NBK = (N + 63) >> 6;            // 64-node buckets
  int M = NBK * NB1;                  // gh/ghs entries
  int chunk = (E + NB1 - 1) / NB1;    // edges per sort block

  char* p = (char*)d_ws;
  size_t o = 0;
  int* deg     = (int*)(p + o); o = align256(o + (size_t)N * 4);
  float* dinv  = (float*)(p + o); o = align256(o + (size_t)N * 4);
  int* gh      = (int*)(p + o); o = align256(o + (size_t)M * 4);
  int* ghs     = (int*)(p + o); o = align256(o + (size_t)M * 4);
  unsigned* recs = (unsigned*)(p + o); o = align256(o + (size_t)E * 4);
  float* xp    = (float*)(p + o); o = align256(o + (size_t)N * 6 * 4);
  float* aggx  = (float*)(p + o); o = align256(o + (size_t)N * 6 * 4);
  unsigned short* Wtf = (unsigned short*)(p + o); o = align256(o + (size_t)4 * 16384 * 2);
  unsigned short* H0  = (unsigned short*)(p + o); o = align256(o + (size_t)N * HDIM * 2);
  unsigned short* H1  = (unsigned short*)(p + o); o = align256(o + (size_t)N * HDIM * 2);
  (void)ws_size;

  // degree / dinv
  init_deg<<<(N + 255) / 256, 256, 0, stream>>>(deg, N);
  hist_kernel<<<(E + 255) / 256, 256, 0, stream>>>(ei, E, deg);
  dinv_kernel<<<(N + 255) / 256, 256, 0, stream>>>(deg, dinv, N);

  // bucket counting sort
  bucket_hist<<<NB1, 1024, 0, stream>>>(ei, E, chunk, gh, NBK);
  scan_kernel<<<1, 256, 0, stream>>>(gh, ghs, M);
  bucket_place<<<NB1, 1024, 0, stream>>>(ei, E, chunk, ghs, recs, NBK);

  // weight prep (independent)
  {
    dim3 g(8, 4);
    wprep_kernel<<<g, 256, 0, stream>>>(W1, W2, Rw0, Rw1, Wtf);
  }

  // layer 0: prescale -> bucket-propagate (6-dim) -> gemm0
  xprescale_kernel<<<(N * 6 + 255) / 256, 256, 0, stream>>>(x, dinv, xp, N * 6);
  prop6b_kernel<<<NBK, 256, 0, stream>>>(xp, dinv, ghs, recs, aggx, N, E, NBK);
  gemm0_kernel<<<(N + 15) / 16, 256, 0, stream>>>(aggx, W0, b0, H0, N);

  int mGrid = (N + 63) / 64;

  // conv1
  mgemm_kernel<0><<<mGrid, 256, 0, stream>>>(H0, Wtf + 0 * 16384, nullptr, H1, N, dinv, nullptr, nullptr, nullptr);
  aggregateb_kernel<<<NBK, 256, 0, stream>>>(H1, dinv, ghs, recs, b1, H0, N, E, NBK);
  // conv2
  mgemm_kernel<0><<<mGrid, 256, 0, stream>>>(H0, Wtf + 1 * 16384, nullptr, H1, N, dinv, nullptr, nullptr, nullptr);
  aggregateb_kernel<<<NBK, 256, 0, stream>>>(H1, dinv, ghs, recs, b2, H0, N, E, NBK);
  // MLP head
  mgemm_kernel<2><<<mGrid, 256, 0, stream>>>(H0, Wtf + 2 * 16384, Rb0, H1, N, nullptr, nullptr, nullptr, nullptr);
  mgemm_kernel<3><<<mGrid, 256, 0, stream>>>(H1, Wtf + 3 * 16384, Rb1, nullptr, N, nullptr, Rw2, Rb2, out);
}

// Round 11
// 372.810 us; speedup vs baseline: 8.1113x; 8.1113x over previous
//
#include <hip/hip_runtime.h>

// GCN on MI355X. R11 = best-measured variant of each stage:
//   R8 fill (int2 {src,w}, 79us) + R8 pull-aggregate (bf16 table, <=79us)
//   + R9 MFMA gemms (bf16 16x16x32) + parallel scan.
// R10's bucket-LDS aggregation reverted: LDS f32 atomics serialized it
// (1362us, VALUBusy 1.9%, occ 20%) — recorded as a dead end.

#define HDIM 128

typedef __attribute__((ext_vector_type(8))) short bf16x8;
typedef __attribute__((ext_vector_type(4))) float f32x4;

__device__ inline unsigned short bf16rn(float f) {
  unsigned u = __float_as_uint(f);
  unsigned r = (u + 0x7FFFu + ((u >> 16) & 1u)) >> 16;
  return (unsigned short)r;
}
__device__ inline float bf16tof(unsigned short h) {
  return __uint_as_float(((unsigned)h) << 16);
}

// ---------------- graph preprocessing ----------------

__global__ void init_deg(int* deg, int n) {
  int i = blockIdx.x * blockDim.x + threadIdx.x;
  if (i < n) deg[i] = 1;  // self loop
}

__global__ void hist_kernel(const int* __restrict__ ei, int E, int* __restrict__ deg) {
  int e = blockIdx.x * blockDim.x + threadIdx.x;
  if (e < E) atomicAdd(&deg[ei[E + e]], 1);  // dst = ei[1][e]
}

__global__ void dinv_kernel(const int* __restrict__ deg, float* __restrict__ dinv, int n) {
  int i = blockIdx.x * blockDim.x + threadIdx.x;
  if (i < n) dinv[i] = rsqrtf((float)deg[i]);
}

// --- parallel exclusive scan of (deg[i]-1), 256 elems/block ---

__global__ __launch_bounds__(256) void block_sums_kernel(const int* __restrict__ deg,
                                                         int* __restrict__ bsums, int n) {
  int i = blockIdx.x * 256 + threadIdx.x;
  int v = (i < n) ? (deg[i] - 1) : 0;
#pragma unroll
  for (int d = 1; d < 64; d <<= 1) v += __shfl_xor(v, d, 64);
  __shared__ int ws[4];
  int lane = threadIdx.x & 63, wid = threadIdx.x >> 6;
  if (lane == 0) ws[wid] = v;
  __syncthreads();
  if (threadIdx.x == 0) bsums[blockIdx.x] = ws[0] + ws[1] + ws[2] + ws[3];
}

__global__ __launch_bounds__(256) void scan_bsums_kernel(const int* __restrict__ bsums,
                                                         int* __restrict__ bscan, int nb) {
  int tid = threadIdx.x, lane = tid & 63, wid = tid >> 6;
  int v = (tid < nb) ? bsums[tid] : 0;
  int inc = v;
#pragma unroll
  for (int d = 1; d < 64; d <<= 1) {
    int t = __shfl_up(inc, (unsigned)d, 64);
    if (lane >= d) inc += t;
  }
  __shared__ int ws[4];
  if (lane == 63) ws[wid] = inc;
  __syncthreads();
  int woff = 0;
  for (int w = 0; w < wid; ++w) woff += ws[w];
  inc += woff;
  if (tid < nb) bscan[tid] = inc - v;
}

__global__ __launch_bounds__(256) void write_off_kernel(const int* __restrict__ deg,
                                                        const int* __restrict__ bscan,
                                                        int* __restrict__ off,
                                                        int* __restrict__ cursor, int n) {
  int i = blockIdx.x * 256 + threadIdx.x;
  int v = (i < n) ? (deg[i] - 1) : 0;
  int lane = threadIdx.x & 63, wid = threadIdx.x >> 6;
  int inc = v;
#pragma unroll
  for (int d = 1; d < 64; d <<= 1) {
    int t = __shfl_up(inc, (unsigned)d, 64);
    if (lane >= d) inc += t;
  }
  __shared__ int ws[4];
  if (lane == 63) ws[wid] = inc;
  __syncthreads();
  int woff = 0;
  for (int w = 0; w < wid; ++w) woff += ws[w];
  inc += woff;
  int base = bscan[blockIdx.x];
  if (i < n) {
    int ex = base + inc - v;
    off[i] = ex;
    cursor[i] = ex;
    if (i == n - 1) off[n] = base + inc;
  }
}

// one 8B record per edge: {src, bits(w)}
__global__ void fill_kernel(const int* __restrict__ ei, int E,
                            const float* __restrict__ dinv,
                            int* __restrict__ cursor, int2* __restrict__ recs) {
  int e = blockIdx.x * blockDim.x + threadIdx.x;
  if (e >= E) return;
  int s = ei[e], d = ei[E + e];
  float w = dinv[s] * dinv[d];
  int pos = atomicAdd(&cursor[d], 1);
  recs[pos] = make_int2(s, __float_as_int(w));
}

// ---------------- layer 0: propagate 6-dim features ----------------
__global__ void prop6_kernel(const float* __restrict__ x, const int* __restrict__ off,
                             const int2* __restrict__ recs,
                             const float* __restrict__ dinv, float* __restrict__ aggx, int n) {
  int g = (blockIdx.x * blockDim.x + threadIdx.x) >> 3;
  int l = threadIdx.x & 7;
  if (g >= n) return;
  float di = dinv[g];
  float acc = 0.f;
  if (l < 6) acc = di * di * x[g * 6 + l];
  int e0 = off[g], e1 = off[g + 1];
  int e = e0;
  for (; e + 4 <= e1; e += 4) {
    int2 r0 = recs[e], r1 = recs[e + 1], r2 = recs[e + 2], r3 = recs[e + 3];
    float u0 = 0.f, u1 = 0.f, u2 = 0.f, u3 = 0.f;
    if (l < 6) {
      u0 = x[r0.x * 6 + l]; u1 = x[r1.x * 6 + l];
      u2 = x[r2.x * 6 + l]; u3 = x[r3.x * 6 + l];
    }
    acc += __int_as_float(r0.y) * u0 + __int_as_float(r1.y) * u1 +
           __int_as_float(r2.y) * u2 + __int_as_float(r3.y) * u3;
  }
  for (; e < e1; ++e) {
    int2 r = recs[e];
    if (l < 6) acc += __int_as_float(r.y) * x[r.x * 6 + l];
  }
  if (l < 6) aggx[g * 6 + l] = acc;
}

// h0 = relu(aggx @ W0 + b0): [n,6]x[6,128] -> bf16. 16 nodes per 256-block.
__global__ __launch_bounds__(256) void gemm0_kernel(const float* __restrict__ aggx,
                                                    const float* __restrict__ W0,
                                                    const float* __restrict__ b0,
                                                    unsigned short* __restrict__ out, int n) {
  __shared__ float Ws[6 * 128];
  __shared__ float bs[128];
  for (int i = threadIdx.x; i < 6 * 128; i += 256) Ws[i] = W0[i];
  if (threadIdx.x < 128) bs[threadIdx.x] = b0[threadIdx.x];
  __syncthreads();
  int f = threadIdx.x & 127;
  int h = threadIdx.x >> 7;
  int base = blockIdx.x * 16;
#pragma unroll
  for (int j = 0; j < 8; ++j) {
    int nd = base + h * 8 + j;
    if (nd < n) {
      float acc = bs[f];
#pragma unroll
      for (int k = 0; k < 6; ++k) acc += aggx[nd * 6 + k] * Ws[k * 128 + f];
      out[(size_t)nd * HDIM + f] = bf16rn(fmaxf(acc, 0.f));
    }
  }
}

// ---------------- weight prep: fp32 W[128][128] -> bf16 fragment order -----
__global__ __launch_bounds__(256) void wprep_kernel(const float* __restrict__ w1,
                                                    const float* __restrict__ w2,
                                                    const float* __restrict__ rw0,
                                                    const float* __restrict__ rw1,
                                                    unsigned short* __restrict__ wtf) {
  int widx = blockIdx.y;
  const float* W = (widx == 0) ? w1 : (widx == 1) ? w2 : (widx == 2) ? rw0 : rw1;
  int c = blockIdx.x * 256 + threadIdx.x;  // 0..2047
  int l = c & 63, kk = (c >> 6) & 3, ft = c >> 8;
  int f = ft * 16 + (l & 15);
  int k0 = kk * 32 + ((l >> 4) << 3);
  unsigned short v[8];
#pragma unroll
  for (int j = 0; j < 8; ++j) v[j] = bf16rn(W[(size_t)(k0 + j) * 128 + f]);
  uint4 pk;
  pk.x = (unsigned)v[0] | ((unsigned)v[1] << 16);
  pk.y = (unsigned)v[2] | ((unsigned)v[3] << 16);
  pk.z = (unsigned)v[4] | ((unsigned)v[5] << 16);
  pk.w = (unsigned)v[6] | ((unsigned)v[7] << 16);
  *(uint4*)&wtf[((size_t)widx * 16384) + (size_t)c * 8] = pk;
}

// ---------------- MFMA GEMM: [n,128](bf16) @ W[128,128] ----------------
// ACT: 0 = raw -> bf16 out; 2 = bias+leaky -> bf16 out;
//      3 = bias+leaky, dot rw2, +rb2 -> fp32 out1[n]
template <int ACT>
__global__ __launch_bounds__(256) void mgemm_kernel(const unsigned short* __restrict__ in,
                                                    const unsigned short* __restrict__ wtf,
                                                    const float* __restrict__ bias,
                                                    unsigned short* __restrict__ out, int n,
                                                    const float* __restrict__ rw2,
                                                    const float* __restrict__ rb2,
                                                    float* __restrict__ out1) {
  __shared__ unsigned short Alds[8192];   // 16KB: swizzled A tile
  __shared__ unsigned short Wlds[16384];  // 32KB fragment-ordered
  int tid = threadIdx.x;
  int rowBase = blockIdx.x * 64;
  {
    const uint4* src = (const uint4*)wtf;
    uint4* dst = (uint4*)Wlds;
#pragma unroll
    for (int c = 0; c < 8; ++c) dst[c * 256 + tid] = src[c * 256 + tid];
  }
  {
    int k8 = tid & 15, tr = tid >> 4;
#pragma unroll
    for (int c = 0; c < 4; ++c) {
      int row = tr + c * 16;
      int gr = rowBase + row;
      uint4 v = make_uint4(0u, 0u, 0u, 0u);
      if (gr < n) v = *(const uint4*)&in[(size_t)gr * HDIM + k8 * 8];
      int srow = row ^ (k8 & 7);
      *(uint4*)&Alds[k8 * 512 + srow * 8] = v;
    }
  }
  __syncthreads();
  int wv = tid >> 6, lane = tid & 63;
  int l16 = lane >> 4, fcol = lane & 15;
  int lrow = wv * 16 + fcol;
  bf16x8 af[4];
#pragma unroll
  for (int kk = 0; kk < 4; ++kk) {
    int k8 = kk * 4 + l16;
    int srow = lrow ^ (k8 & 7);
    af[kk] = *(const bf16x8*)&Alds[k8 * 512 + srow * 8];
  }
  f32x4 acc[8];
#pragma unroll
  for (int ft = 0; ft < 8; ++ft) acc[ft] = (f32x4)(0.f);
#pragma unroll
  for (int ft = 0; ft < 8; ++ft) {
#pragma unroll
    for (int kk = 0; kk < 4; ++kk) {
      bf16x8 bfr = *(const bf16x8*)&Wlds[(((ft * 4 + kk) * 64) + lane) * 8];
      acc[ft] = __builtin_amdgcn_mfma_f32_16x16x32_bf16(af[kk], bfr, acc[ft], 0, 0, 0);
    }
  }
  int orow0 = rowBase + wv * 16 + l16 * 4;  // D: col=lane&15, row=(lane>>4)*4+reg

  if (ACT == 3) {
    float p[4] = {0.f, 0.f, 0.f, 0.f};
#pragma unroll
    for (int ft = 0; ft < 8; ++ft) {
      int f = ft * 16 + fcol;
      float bb = bias[f], ww = rw2[f];
#pragma unroll
      for (int r = 0; r < 4; ++r) {
        float v = acc[ft][r] + bb;
        v = v > 0.f ? v : 0.01f * v;
        p[r] += v * ww;
      }
    }
#pragma unroll
    for (int d = 1; d < 16; d <<= 1) {
#pragma unroll
      for (int r = 0; r < 4; ++r) p[r] += __shfl_xor(p[r], d, 64);
    }
    if (fcol == 0) {
      float rb = rb2[0];
#pragma unroll
      for (int r = 0; r < 4; ++r) {
        int row = orow0 + r;
        if (row < n) out1[row] = p[r] + rb;
      }
    }
    return;
  }

#pragma unroll
  for (int ft = 0; ft < 8; ++ft) {
    int f = ft * 16 + fcol;
    float bb = (ACT == 2) ? bias[f] : 0.f;
#pragma unroll
    for (int r = 0; r < 4; ++r) {
      int row = orow0 + r;
      if (row < n) {
        float v = acc[ft][r];
        if (ACT == 2) {
          v += bb;
          v = v > 0.f ? v : 0.01f * v;
        }
        out[(size_t)row * HDIM + f] = bf16rn(v);
      }
    }
  }
}

// ---------------- aggregation (pull, CSR): one wave per node, bf16 table ----
__global__ __launch_bounds__(256) void aggregate_kernel(const unsigned short* __restrict__ t,
                                                        const int* __restrict__ off,
                                                        const int2* __restrict__ recs,
                                                        const float* __restrict__ dinv,
                                                        const float* __restrict__ bias,
                                                        unsigned short* __restrict__ out, int n) {
  int node = (blockIdx.x * blockDim.x + threadIdx.x) >> 6;
  int lane = threadIdx.x & 63;
  if (node >= n) return;
  const ushort2* tf = (const ushort2*)t + lane;  // row r at tf[r*64]
  float di = dinv[node];
  float self = di * di;
  ushort2 v = tf[(size_t)node * 64];
  float ax = self * bf16tof(v.x), ay = self * bf16tof(v.y);
  int e0 = off[node], e1 = off[node + 1];
  int e = e0;
  for (; e + 8 <= e1; e += 8) {
    int2 r[8];
    ushort2 u[8];
#pragma unroll
    for (int j = 0; j < 8; ++j) r[j] = recs[e + j];
#pragma unroll
    for (int j = 0; j < 8; ++j) u[j] = tf[(size_t)r[j].x * 64];
#pragma unroll
    for (int j = 0; j < 8; ++j) {
      float w = __int_as_float(r[j].y);
      ax += w * bf16tof(u[j].x);
      ay += w * bf16tof(u[j].y);
    }
  }
  for (; e < e1; ++e) {
    int2 r = recs[e];
    float w = __int_as_float(r.y);
    ushort2 u = tf[(size_t)r.x * 64];
    ax += w * bf16tof(u.x);
    ay += w * bf16tof(u.y);
  }
  const float2* bf = (const float2*)bias + lane;
  float2 b = *bf;
  ax = fmaxf(ax + b.x, 0.f);
  ay = fmaxf(ay + b.y, 0.f);
  ushort2 o;
  o.x = bf16rn(ax);
  o.y = bf16rn(ay);
  *((ushort2*)out + (size_t)node * 64 + lane) = o;
}

// ---------------- host ----------------

static inline size_t align256(size_t x) { return (x + 255) & ~(size_t)255; }

extern "C" void kernel_launch(void* const* d_in, const int* in_sizes, int n_in,
                              void* d_out, int out_size, void* d_ws, size_t ws_size,
                              hipStream_t stream) {
  const float* x   = (const float*)d_in[0];
  const int*   ei  = (const int*)d_in[1];
  const float* W0  = (const float*)d_in[2];
  const float* b0  = (const float*)d_in[3];
  const float* W1  = (const float*)d_in[4];
  const float* b1  = (const float*)d_in[5];
  const float* W2  = (const float*)d_in[6];
  const float* b2  = (const float*)d_in[7];
  const float* Rw0 = (const float*)d_in[8];
  const float* Rb0 = (const float*)d_in[9];
  const float* Rw1 = (const float*)d_in[10];
  const float* Rb1 = (const float*)d_in[11];
  const float* Rw2 = (const float*)d_in[12];
  const float* Rb2 = (const float*)d_in[13];
  float* out = (float*)d_out;

  int N = in_sizes[0] / 6;
  int E = in_sizes[1] / 2;
  int NB = (N + 255) / 256;

  char* p = (char*)d_ws;
  size_t o = 0;
  int* deg     = (int*)(p + o); o = align256(o + (size_t)N * 4);
  int* cursor  = (int*)(p + o); o = align256(o + (size_t)N * 4);
  int* off     = (int*)(p + o); o = align256(o + (size_t)(N + 1) * 4);
  float* dinv  = (float*)(p + o); o = align256(o + (size_t)N * 4);
  int* bsums   = (int*)(p + o); o = align256(o + (size_t)NB * 4);
  int* bscan   = (int*)(p + o); o = align256(o + (size_t)NB * 4);
  int2* recs   = (int2*)(p + o); o = align256(o + (size_t)E * 8);
  float* aggx  = (float*)(p + o); o = align256(o + (size_t)N * 6 * 4);
  unsigned short* Wtf = (unsigned short*)(p + o); o = align256(o + (size_t)4 * 16384 * 2);
  unsigned short* H0  = (unsigned short*)(p + o); o = align256(o + (size_t)N * HDIM * 2);
  unsigned short* H1  = (unsigned short*)(p + o); o = align256(o + (size_t)N * HDIM * 2);
  (void)ws_size;

  // graph prep
  init_deg<<<(N + 255) / 256, 256, 0, stream>>>(deg, N);
  hist_kernel<<<(E + 255) / 256, 256, 0, stream>>>(ei, E, deg);
  dinv_kernel<<<(N + 255) / 256, 256, 0, stream>>>(deg, dinv, N);
  block_sums_kernel<<<NB, 256, 0, stream>>>(deg, bsums, N);
  scan_bsums_kernel<<<1, 256, 0, stream>>>(bsums, bscan, NB);
  write_off_kernel<<<NB, 256, 0, stream>>>(deg, bscan, off, cursor, N);
  fill_kernel<<<(E + 255) / 256, 256, 0, stream>>>(ei, E, dinv, cursor, recs);

  // weight prep (independent)
  {
    dim3 g(8, 4);
    wprep_kernel<<<g, 256, 0, stream>>>(W1, W2, Rw0, Rw1, Wtf);
  }

  // layer 0: propagate in 6-dim, then 6->128 gemm + relu -> bf16
  prop6_kernel<<<(N + 31) / 32, 256, 0, stream>>>(x, off, recs, dinv, aggx, N);
  gemm0_kernel<<<(N + 15) / 16, 256, 0, stream>>>(aggx, W0, b0, H0, N);

  int mGrid = (N + 63) / 64;
  int aggGrid = (N + 3) / 4;

  // conv1
  mgemm_kernel<0><<<mGrid, 256, 0, stream>>>(H0, Wtf + 0 * 16384, nullptr, H1, N, nullptr, nullptr, nullptr);
  aggregate_kernel<<<aggGrid, 256, 0, stream>>>(H1, off, recs, dinv, b1, H0, N);
  // conv2
  mgemm_kernel<0><<<mGrid, 256, 0, stream>>>(H0, Wtf + 1 * 16384, nullptr, H1, N, nullptr, nullptr, nullptr);
  aggregate_kernel<<<aggGrid, 256, 0, stream>>>(H1, off, recs, dinv, b2, H0, N);
  // MLP head
  mgemm_kernel<2><<<mGrid, 256, 0, stream>>>(H0, Wtf + 2 * 16384, Rb0, H1, N, nullptr, nullptr, nullptr);
  mgemm_kernel<3><<<mGrid, 256, 0, stream>>>(H1, Wtf + 3 * 16384, Rb1, nullptr, N, Rw2, Rb2, out);
}